// Round 1
// baseline (232.407 us; speedup 1.0000x reference)
//
#include <hip/hip_runtime.h>
#include <math.h>

#define C_CH 256
#define RESO 7
#define NBIN 49   // 7*7

// ---------------------------------------------------------------------------
// Transpose NCHW -> NHWC per level.  src: [2][256][HW], dst: [2][HW][256]
// Tile: 32 channels x 32 hw.  Block (8,32) = 256 threads.
// VEC=true requires HW % 4 == 0 (levels 0..2).
// ---------------------------------------------------------------------------
template <bool VEC>
__global__ __launch_bounds__(256) void transpose_nchw_nhwc(
    const float* __restrict__ src, float* __restrict__ dst, int HW) {
  __shared__ float tile[32][33];  // [c_local][hw_local], +1 pad
  const int tx = threadIdx.x;     // 0..7
  const int ty = threadIdx.y;     // 0..31
  const int hw0 = blockIdx.x * 32;
  const int c0 = blockIdx.y * 32;
  const int n = blockIdx.z;

  const float* s = src + (size_t)n * C_CH * HW;
  float* d = dst + (size_t)n * HW * C_CH;

  // load: coalesced along hw
  if (VEC) {
    const int hw = hw0 + tx * 4;
    if (hw + 3 < HW) {
      const float4 v = *(const float4*)(s + (size_t)(c0 + ty) * HW + hw);
      tile[ty][tx * 4 + 0] = v.x;
      tile[ty][tx * 4 + 1] = v.y;
      tile[ty][tx * 4 + 2] = v.z;
      tile[ty][tx * 4 + 3] = v.w;
    } else {
      for (int k = 0; k < 4; ++k)
        if (hw + k < HW) tile[ty][tx * 4 + k] = s[(size_t)(c0 + ty) * HW + hw + k];
    }
  } else {
    for (int k = 0; k < 4; ++k) {
      const int hw = hw0 + tx + 8 * k;
      if (hw < HW) tile[ty][tx + 8 * k] = s[(size_t)(c0 + ty) * HW + hw];
    }
  }
  __syncthreads();

  // store: coalesced along c
  const int hw = hw0 + ty;
  if (hw < HW) {
    if (VEC) {
      float4 v;
      v.x = tile[tx * 4 + 0][ty];
      v.y = tile[tx * 4 + 1][ty];
      v.z = tile[tx * 4 + 2][ty];
      v.w = tile[tx * 4 + 3][ty];
      *(float4*)(d + (size_t)hw * C_CH + c0 + tx * 4) = v;
    } else {
      for (int k = 0; k < 4; ++k)
        d[(size_t)hw * C_CH + c0 + tx + 8 * k] = tile[tx + 8 * k][ty];
    }
  }
}

// ---------------------------------------------------------------------------
// RoIAlign gather.  One block per ROI (1024 blocks, 256 threads).
// NHWC=1: features are [2][H][W][256] in workspace; lane handles 4 channels
//         (float4 taps), waves 0..3 split the 49 bins.
// NHWC=0: fallback, features are original NCHW pointers (slow but correct).
// ---------------------------------------------------------------------------
template <int NHWC>
__global__ __launch_bounds__(256) void roi_gather(
    const float* __restrict__ f0, const float* __restrict__ f1,
    const float* __restrict__ f2, const float* __restrict__ f3,
    const float* __restrict__ props0, const float* __restrict__ props1,
    float* __restrict__ out) {
  __shared__ float obuf[NBIN * C_CH];      // c-major: obuf[c*49 + bin]
  __shared__ int s_o0[2][14], s_o1[2][14]; // pre-scaled lo/hi offsets (0=y,1=x)
  __shared__ float s_w0[2][14], s_w1[2][14];  // weights with validity folded in

  const int r = blockIdx.x;
  const int t = threadIdx.x;
  const int b = (r >= 512) ? 1 : 0;
  const float* pr = (b ? props1 : props0) + (r & 511) * 4;
  const float x1 = pr[0], y1 = pr[1], x2 = pr[2], y2 = pr[3];

  // level assignment (must match numpy f32 math)
  const float size = sqrtf((x2 - x1 + 1.0f) * (y2 - y1 + 1.0f));
  float lv = floorf(4.0f + log2f(size / 224.0f + 1e-6f));
  lv = fminf(fmaxf(lv, 2.0f), 5.0f) - 2.0f;
  const int lvl = (int)lv;

  const int Htab[4] = {200, 100, 50, 25};
  const float stab[4] = {0.25f, 0.125f, 0.0625f, 0.03125f};
  const int H = Htab[lvl];
  const int W = H;
  const float sc = stab[lvl];
  const float* fl = (lvl == 0) ? f0 : (lvl == 1) ? f1 : (lvl == 2) ? f2 : f3;

  const float rx1 = x1 * sc, ry1 = y1 * sc;
  const float roi_w = fmaxf(x2 * sc - rx1, 1.0f);
  const float roi_h = fmaxf(y2 * sc - ry1, 1.0f);
  const float bw = roi_w / 7.0f, bh = roi_h / 7.0f;

  if (t < 28) {
    const int axis = t / 14;  // 0 = y, 1 = x
    const int k = t % 14;
    const float off = ((float)k + 0.5f) * 0.5f;  // (k+0.5)/SAMPLE_RATIO, exact
    const float v = axis ? (rx1 + off * bw) : (ry1 + off * bh);
    const int isz = H;  // H == W
    const bool valid = (v >= -1.0f) && (v <= (float)isz);
    const float v0 = fmaxf(v, 0.0f);
    int lo = (int)floorf(v0);
    const bool edge = (lo >= isz - 1);
    lo = edge ? isz - 1 : lo;
    const int hi = edge ? isz - 1 : lo + 1;
    const float fr = edge ? 0.0f : (v0 - (float)lo);
    const int mul = axis ? (NHWC ? C_CH : 1) : (NHWC ? W * C_CH : W);
    s_o0[axis][k] = lo * mul;
    s_o1[axis][k] = hi * mul;
    s_w1[axis][k] = valid ? fr : 0.0f;
    s_w0[axis][k] = valid ? (1.0f - fr) : 0.0f;
  }
  __syncthreads();

  const int wv = t >> 6;    // wave id 0..3: splits bins
  const int ln = t & 63;    // lane: 4 channels each
  const size_t HWp = (size_t)H * W;

  if (NHWC) {
    const float* base = fl + (size_t)b * HWp * C_CH + ln * 4;
    for (int bb = wv; bb < NBIN; bb += 4) {
      const int ph = bb / 7, pw = bb - ph * 7;
      float4 acc = make_float4(0.f, 0.f, 0.f, 0.f);
#pragma unroll
      for (int s1 = 0; s1 < 2; ++s1) {
        const int sy = 2 * ph + s1;
        const int yo0 = s_o0[0][sy], yo1 = s_o1[0][sy];
        const float wy0 = s_w0[0][sy], wy1 = s_w1[0][sy];
#pragma unroll
        for (int s2 = 0; s2 < 2; ++s2) {
          const int sx = 2 * pw + s2;
          const int xo0 = s_o0[1][sx], xo1 = s_o1[1][sx];
          const float wx0 = s_w0[1][sx], wx1 = s_w1[1][sx];
          const float4 p00 = *(const float4*)(base + yo0 + xo0);
          const float4 p01 = *(const float4*)(base + yo0 + xo1);
          const float4 p10 = *(const float4*)(base + yo1 + xo0);
          const float4 p11 = *(const float4*)(base + yo1 + xo1);
          acc.x += wy0 * (wx0 * p00.x + wx1 * p01.x) + wy1 * (wx0 * p10.x + wx1 * p11.x);
          acc.y += wy0 * (wx0 * p00.y + wx1 * p01.y) + wy1 * (wx0 * p10.y + wx1 * p11.y);
          acc.z += wy0 * (wx0 * p00.z + wx1 * p01.z) + wy1 * (wx0 * p10.z + wx1 * p11.z);
          acc.w += wy0 * (wx0 * p00.w + wx1 * p01.w) + wy1 * (wx0 * p10.w + wx1 * p11.w);
        }
      }
      const int c4 = ln * 4;
      obuf[(c4 + 0) * NBIN + bb] = acc.x * 0.25f;
      obuf[(c4 + 1) * NBIN + bb] = acc.y * 0.25f;
      obuf[(c4 + 2) * NBIN + bb] = acc.z * 0.25f;
      obuf[(c4 + 3) * NBIN + bb] = acc.w * 0.25f;
    }
  } else {
    const float* base = fl + ((size_t)b * C_CH + ln * 4) * HWp;
    for (int bb = wv; bb < NBIN; bb += 4) {
      const int ph = bb / 7, pw = bb - ph * 7;
      float4 acc = make_float4(0.f, 0.f, 0.f, 0.f);
#pragma unroll
      for (int s1 = 0; s1 < 2; ++s1) {
        const int sy = 2 * ph + s1;
        const int yo0 = s_o0[0][sy], yo1 = s_o1[0][sy];
        const float wy0 = s_w0[0][sy], wy1 = s_w1[0][sy];
#pragma unroll
        for (int s2 = 0; s2 < 2; ++s2) {
          const int sx = 2 * pw + s2;
          const int xo0 = s_o0[1][sx], xo1 = s_o1[1][sx];
          const float wx0 = s_w0[1][sx], wx1 = s_w1[1][sx];
#pragma unroll
          for (int j = 0; j < 4; ++j) {
            const float p00 = base[j * HWp + yo0 + xo0];
            const float p01 = base[j * HWp + yo0 + xo1];
            const float p10 = base[j * HWp + yo1 + xo0];
            const float p11 = base[j * HWp + yo1 + xo1];
            const float e = wy0 * (wx0 * p00 + wx1 * p01) + wy1 * (wx0 * p10 + wx1 * p11);
            if (j == 0) acc.x += e;
            if (j == 1) acc.y += e;
            if (j == 2) acc.z += e;
            if (j == 3) acc.w += e;
          }
        }
      }
      const int c4 = ln * 4;
      obuf[(c4 + 0) * NBIN + bb] = acc.x * 0.25f;
      obuf[(c4 + 1) * NBIN + bb] = acc.y * 0.25f;
      obuf[(c4 + 2) * NBIN + bb] = acc.z * 0.25f;
      obuf[(c4 + 3) * NBIN + bb] = acc.w * 0.25f;
    }
  }
  __syncthreads();

  // coalesced write-out: out[r] is 12544 contiguous floats
  float4* o4 = (float4*)(out + (size_t)r * (NBIN * C_CH));
  const float4* ob4 = (const float4*)obuf;
  for (int i = t; i < NBIN * C_CH / 4; i += 256) o4[i] = ob4[i];
}

// ---------------------------------------------------------------------------
extern "C" void kernel_launch(void* const* d_in, const int* in_sizes, int n_in,
                              void* d_out, int out_size, void* d_ws, size_t ws_size,
                              hipStream_t stream) {
  const float* f0 = (const float*)d_in[0];
  const float* f1 = (const float*)d_in[1];
  const float* f2 = (const float*)d_in[2];
  const float* f3 = (const float*)d_in[3];
  // d_in[4] (feat4, 13x13) is unused by the reference (only 4 RATIOS levels)
  const float* p0 = (const float*)d_in[5];
  const float* p1 = (const float*)d_in[6];
  float* out = (float*)d_out;
  float* ws = (float*)d_ws;

  const int HWs[4] = {200 * 200, 100 * 100, 50 * 50, 25 * 25};
  size_t off[4];
  size_t acc = 0;
  for (int l = 0; l < 4; ++l) {
    off[l] = acc;
    acc += (size_t)2 * C_CH * HWs[l];
  }
  const size_t need_bytes = acc * sizeof(float);  // 108.8 MB

  if (ws_size >= need_bytes) {
    const float* srcs[4] = {f0, f1, f2, f3};
    for (int l = 0; l < 4; ++l) {
      dim3 grid((HWs[l] + 31) / 32, 8, 2);
      dim3 block(8, 32);
      if (HWs[l] % 4 == 0)
        transpose_nchw_nhwc<true><<<grid, block, 0, stream>>>(srcs[l], ws + off[l], HWs[l]);
      else
        transpose_nchw_nhwc<false><<<grid, block, 0, stream>>>(srcs[l], ws + off[l], HWs[l]);
    }
    roi_gather<1><<<1024, 256, 0, stream>>>(ws + off[0], ws + off[1], ws + off[2],
                                            ws + off[3], p0, p1, out);
  } else {
    roi_gather<0><<<1024, 256, 0, stream>>>(f0, f1, f2, f3, p0, p1, out);
  }
}

// Round 2
// 209.359 us; speedup vs baseline: 1.1101x; 1.1101x over previous
//
#include <hip/hip_runtime.h>
#include <math.h>

#define C_CH 256
#define RESO 7
#define NBIN 49   // 7*7

// f32 -> bf16, round-to-nearest-even
__device__ __forceinline__ unsigned short f2bf(float f) {
  unsigned int u = __float_as_uint(f);
  u = (u + 0x7fffu + ((u >> 16) & 1u)) >> 16;
  return (unsigned short)u;
}
__device__ __forceinline__ float bf_lo(unsigned int u) { return __uint_as_float(u << 16); }
__device__ __forceinline__ float bf_hi(unsigned int u) { return __uint_as_float(u & 0xffff0000u); }

// ---------------------------------------------------------------------------
// Merged NCHW(f32) -> NHWC(bf16) conversion for all 4 levels, one dispatch.
// src[l]: [2][256][HW_l] f32 ; dst[l]: [2][HW_l][256] bf16.
// Tile: 32 channels x 32 hw. Block (8,32) = 256 threads.
// ---------------------------------------------------------------------------
struct TArgs {
  const float* src[4];
  unsigned short* dst[4];
  int hw[4];
  int bx0[5];  // cumulative grid.x block start per level
};

__global__ __launch_bounds__(256) void conv_nhwc_bf16(TArgs a) {
  __shared__ float tile[32][33];  // [c_local][hw_local], +1 pad
  const int bx = blockIdx.x;
  int l = 0;
  if (bx >= a.bx0[1]) l = 1;
  if (bx >= a.bx0[2]) l = 2;
  if (bx >= a.bx0[3]) l = 3;
  const int HW = a.hw[l];
  const int hw0 = (bx - a.bx0[l]) * 32;
  const int c0 = blockIdx.y * 32;
  const int n = blockIdx.z;

  const float* s = a.src[l] + (size_t)n * C_CH * HW;
  unsigned short* d = a.dst[l] + (size_t)n * HW * C_CH;

  const int tx = threadIdx.x;  // 0..7
  const int ty = threadIdx.y;  // 0..31

  // load: coalesced along hw.  float4 only when rows are 16B-aligned (HW%4==0).
  if ((HW & 3) == 0) {
    const int hw = hw0 + tx * 4;
    if (hw + 3 < HW) {
      const float4 v = *(const float4*)(s + (size_t)(c0 + ty) * HW + hw);
      tile[ty][tx * 4 + 0] = v.x;
      tile[ty][tx * 4 + 1] = v.y;
      tile[ty][tx * 4 + 2] = v.z;
      tile[ty][tx * 4 + 3] = v.w;
    } else {
      for (int k = 0; k < 4; ++k)
        if (hw + k < HW) tile[ty][tx * 4 + k] = s[(size_t)(c0 + ty) * HW + hw + k];
    }
  } else {
    for (int k = 0; k < 4; ++k) {
      const int hw = hw0 + tx + 8 * k;
      if (hw < HW) tile[ty][tx + 8 * k] = s[(size_t)(c0 + ty) * HW + hw];
    }
  }
  __syncthreads();

  // store: 4 bf16 (8B) per thread, 64B contiguous per 8 threads
  const int hww = hw0 + ty;
  if (hww < HW) {
    unsigned int lo = (unsigned int)f2bf(tile[tx * 4 + 0][ty]) |
                      ((unsigned int)f2bf(tile[tx * 4 + 1][ty]) << 16);
    unsigned int hi = (unsigned int)f2bf(tile[tx * 4 + 2][ty]) |
                      ((unsigned int)f2bf(tile[tx * 4 + 3][ty]) << 16);
    uint2 v = make_uint2(lo, hi);
    *(uint2*)(d + (size_t)hww * C_CH + c0 + tx * 4) = v;
  }
}

// ---------------------------------------------------------------------------
// RoIAlign gather from bf16 NHWC workspace. One block per ROI, 256 threads.
// lane = 4 channels (uint2 = 4 bf16 per tap), waves 0..3 split the 49 bins.
// ---------------------------------------------------------------------------
__global__ __launch_bounds__(256) void roi_gather_bf16(
    const unsigned short* __restrict__ f0, const unsigned short* __restrict__ f1,
    const unsigned short* __restrict__ f2, const unsigned short* __restrict__ f3,
    const float* __restrict__ props0, const float* __restrict__ props1,
    float* __restrict__ out) {
  __shared__ float obuf[NBIN * C_CH];       // c-major: obuf[c*49 + bin]
  __shared__ int s_o0[2][14], s_o1[2][14];  // pre-scaled lo/hi offsets (0=y,1=x)
  __shared__ float s_w0[2][14], s_w1[2][14];

  const int r = blockIdx.x;
  const int t = threadIdx.x;
  const int b = (r >= 512) ? 1 : 0;
  const float* pr = (b ? props1 : props0) + (r & 511) * 4;
  const float x1 = pr[0], y1 = pr[1], x2 = pr[2], y2 = pr[3];

  // level assignment (match numpy f32 math exactly)
  const float size = sqrtf((x2 - x1 + 1.0f) * (y2 - y1 + 1.0f));
  float lv = floorf(4.0f + log2f(size / 224.0f + 1e-6f));
  lv = fminf(fmaxf(lv, 2.0f), 5.0f) - 2.0f;
  const int lvl = (int)lv;

  const int Htab[4] = {200, 100, 50, 25};
  const float stab[4] = {0.25f, 0.125f, 0.0625f, 0.03125f};
  const int H = Htab[lvl];
  const int W = H;
  const float sc = stab[lvl];
  const unsigned short* fl = (lvl == 0) ? f0 : (lvl == 1) ? f1 : (lvl == 2) ? f2 : f3;

  const float rx1 = x1 * sc, ry1 = y1 * sc;
  const float roi_w = fmaxf(x2 * sc - rx1, 1.0f);
  const float roi_h = fmaxf(y2 * sc - ry1, 1.0f);
  const float bw = roi_w / 7.0f, bh = roi_h / 7.0f;

  if (t < 28) {
    const int axis = t / 14;  // 0 = y, 1 = x
    const int k = t % 14;
    const float off = ((float)k + 0.5f) * 0.5f;
    const float v = axis ? (rx1 + off * bw) : (ry1 + off * bh);
    const int isz = H;
    const bool valid = (v >= -1.0f) && (v <= (float)isz);
    const float v0 = fmaxf(v, 0.0f);
    int lo = (int)floorf(v0);
    const bool edge = (lo >= isz - 1);
    lo = edge ? isz - 1 : lo;
    const int hi = edge ? isz - 1 : lo + 1;
    const float fr = edge ? 0.0f : (v0 - (float)lo);
    const int mul = axis ? C_CH : W * C_CH;
    s_o0[axis][k] = lo * mul;
    s_o1[axis][k] = hi * mul;
    s_w1[axis][k] = valid ? fr : 0.0f;
    s_w0[axis][k] = valid ? (1.0f - fr) : 0.0f;
  }
  __syncthreads();

  const int wv = t >> 6;  // wave id 0..3: splits bins
  const int ln = t & 63;  // lane: 4 channels each
  const size_t HWp = (size_t)H * W;

  const unsigned short* base = fl + (size_t)b * HWp * C_CH + ln * 4;
  for (int bb = wv; bb < NBIN; bb += 4) {
    const int ph = bb / 7, pw = bb - ph * 7;
    float4 acc = make_float4(0.f, 0.f, 0.f, 0.f);
#pragma unroll
    for (int s1 = 0; s1 < 2; ++s1) {
      const int sy = 2 * ph + s1;
      const int yo0 = s_o0[0][sy], yo1 = s_o1[0][sy];
      const float wy0 = s_w0[0][sy], wy1 = s_w1[0][sy];
#pragma unroll
      for (int s2 = 0; s2 < 2; ++s2) {
        const int sx = 2 * pw + s2;
        const int xo0 = s_o0[1][sx], xo1 = s_o1[1][sx];
        const float w00 = wy0 * s_w0[1][sx], w01 = wy0 * s_w1[1][sx];
        const float w10 = wy1 * s_w0[1][sx], w11 = wy1 * s_w1[1][sx];
        const uint2 q00 = *(const uint2*)(base + yo0 + xo0);
        const uint2 q01 = *(const uint2*)(base + yo0 + xo1);
        const uint2 q10 = *(const uint2*)(base + yo1 + xo0);
        const uint2 q11 = *(const uint2*)(base + yo1 + xo1);
        acc.x += w00 * bf_lo(q00.x) + w01 * bf_lo(q01.x) + w10 * bf_lo(q10.x) + w11 * bf_lo(q11.x);
        acc.y += w00 * bf_hi(q00.x) + w01 * bf_hi(q01.x) + w10 * bf_hi(q10.x) + w11 * bf_hi(q11.x);
        acc.z += w00 * bf_lo(q00.y) + w01 * bf_lo(q01.y) + w10 * bf_lo(q10.y) + w11 * bf_lo(q11.y);
        acc.w += w00 * bf_hi(q00.y) + w01 * bf_hi(q01.y) + w10 * bf_hi(q10.y) + w11 * bf_hi(q11.y);
      }
    }
    const int c4 = ln * 4;
    obuf[(c4 + 0) * NBIN + bb] = acc.x * 0.25f;
    obuf[(c4 + 1) * NBIN + bb] = acc.y * 0.25f;
    obuf[(c4 + 2) * NBIN + bb] = acc.z * 0.25f;
    obuf[(c4 + 3) * NBIN + bb] = acc.w * 0.25f;
  }
  __syncthreads();

  // coalesced write-out: out[r] is 12544 contiguous floats
  float4* o4 = (float4*)(out + (size_t)r * (NBIN * C_CH));
  const float4* ob4 = (const float4*)obuf;
  for (int i = t; i < NBIN * C_CH / 4; i += 256) o4[i] = ob4[i];
}

// ---------------------------------------------------------------------------
// Fallback: direct NCHW f32 gather (used only if workspace is too small).
// ---------------------------------------------------------------------------
__global__ __launch_bounds__(256) void roi_gather_nchw(
    const float* __restrict__ f0, const float* __restrict__ f1,
    const float* __restrict__ f2, const float* __restrict__ f3,
    const float* __restrict__ props0, const float* __restrict__ props1,
    float* __restrict__ out) {
  __shared__ float obuf[NBIN * C_CH];
  __shared__ int s_o0[2][14], s_o1[2][14];
  __shared__ float s_w0[2][14], s_w1[2][14];

  const int r = blockIdx.x;
  const int t = threadIdx.x;
  const int b = (r >= 512) ? 1 : 0;
  const float* pr = (b ? props1 : props0) + (r & 511) * 4;
  const float x1 = pr[0], y1 = pr[1], x2 = pr[2], y2 = pr[3];
  const float size = sqrtf((x2 - x1 + 1.0f) * (y2 - y1 + 1.0f));
  float lv = floorf(4.0f + log2f(size / 224.0f + 1e-6f));
  lv = fminf(fmaxf(lv, 2.0f), 5.0f) - 2.0f;
  const int lvl = (int)lv;
  const int Htab[4] = {200, 100, 50, 25};
  const float stab[4] = {0.25f, 0.125f, 0.0625f, 0.03125f};
  const int H = Htab[lvl];
  const int W = H;
  const float sc = stab[lvl];
  const float* fl = (lvl == 0) ? f0 : (lvl == 1) ? f1 : (lvl == 2) ? f2 : f3;
  const float rx1 = x1 * sc, ry1 = y1 * sc;
  const float roi_w = fmaxf(x2 * sc - rx1, 1.0f);
  const float roi_h = fmaxf(y2 * sc - ry1, 1.0f);
  const float bw = roi_w / 7.0f, bh = roi_h / 7.0f;
  if (t < 28) {
    const int axis = t / 14;
    const int k = t % 14;
    const float off = ((float)k + 0.5f) * 0.5f;
    const float v = axis ? (rx1 + off * bw) : (ry1 + off * bh);
    const int isz = H;
    const bool valid = (v >= -1.0f) && (v <= (float)isz);
    const float v0 = fmaxf(v, 0.0f);
    int lo = (int)floorf(v0);
    const bool edge = (lo >= isz - 1);
    lo = edge ? isz - 1 : lo;
    const int hi = edge ? isz - 1 : lo + 1;
    const float fr = edge ? 0.0f : (v0 - (float)lo);
    const int mul = axis ? 1 : W;
    s_o0[axis][k] = lo * mul;
    s_o1[axis][k] = hi * mul;
    s_w1[axis][k] = valid ? fr : 0.0f;
    s_w0[axis][k] = valid ? (1.0f - fr) : 0.0f;
  }
  __syncthreads();
  const int wv = t >> 6;
  const int ln = t & 63;
  const size_t HWp = (size_t)H * W;
  const float* base = fl + ((size_t)b * C_CH + ln * 4) * HWp;
  for (int bb = wv; bb < NBIN; bb += 4) {
    const int ph = bb / 7, pw = bb - ph * 7;
    float4 acc = make_float4(0.f, 0.f, 0.f, 0.f);
    for (int s1 = 0; s1 < 2; ++s1) {
      const int sy = 2 * ph + s1;
      const int yo0 = s_o0[0][sy], yo1 = s_o1[0][sy];
      const float wy0 = s_w0[0][sy], wy1 = s_w1[0][sy];
      for (int s2 = 0; s2 < 2; ++s2) {
        const int sx = 2 * pw + s2;
        const int xo0 = s_o0[1][sx], xo1 = s_o1[1][sx];
        const float w00 = wy0 * s_w0[1][sx], w01 = wy0 * s_w1[1][sx];
        const float w10 = wy1 * s_w0[1][sx], w11 = wy1 * s_w1[1][sx];
        float e[4];
        for (int j = 0; j < 4; ++j) {
          e[j] = w00 * base[j * HWp + yo0 + xo0] + w01 * base[j * HWp + yo0 + xo1] +
                 w10 * base[j * HWp + yo1 + xo0] + w11 * base[j * HWp + yo1 + xo1];
        }
        acc.x += e[0]; acc.y += e[1]; acc.z += e[2]; acc.w += e[3];
      }
    }
    const int c4 = ln * 4;
    obuf[(c4 + 0) * NBIN + bb] = acc.x * 0.25f;
    obuf[(c4 + 1) * NBIN + bb] = acc.y * 0.25f;
    obuf[(c4 + 2) * NBIN + bb] = acc.z * 0.25f;
    obuf[(c4 + 3) * NBIN + bb] = acc.w * 0.25f;
  }
  __syncthreads();
  float4* o4 = (float4*)(out + (size_t)r * (NBIN * C_CH));
  const float4* ob4 = (const float4*)obuf;
  for (int i = t; i < NBIN * C_CH / 4; i += 256) o4[i] = ob4[i];
}

// ---------------------------------------------------------------------------
extern "C" void kernel_launch(void* const* d_in, const int* in_sizes, int n_in,
                              void* d_out, int out_size, void* d_ws, size_t ws_size,
                              hipStream_t stream) {
  const float* f0 = (const float*)d_in[0];
  const float* f1 = (const float*)d_in[1];
  const float* f2 = (const float*)d_in[2];
  const float* f3 = (const float*)d_in[3];
  // d_in[4] (feat4, 13x13) unused by reference
  const float* p0 = (const float*)d_in[5];
  const float* p1 = (const float*)d_in[6];
  float* out = (float*)d_out;
  unsigned short* ws = (unsigned short*)d_ws;

  const int HWs[4] = {200 * 200, 100 * 100, 50 * 50, 25 * 25};
  size_t off[4];
  size_t acc = 0;
  for (int l = 0; l < 4; ++l) {
    off[l] = acc;
    acc += (size_t)2 * C_CH * HWs[l];
  }
  const size_t need_bytes = acc * sizeof(unsigned short);  // ~54.4 MB

  if (ws_size >= need_bytes) {
    TArgs a;
    a.src[0] = f0; a.src[1] = f1; a.src[2] = f2; a.src[3] = f3;
    int cum = 0;
    for (int l = 0; l < 4; ++l) {
      a.dst[l] = ws + off[l];
      a.hw[l] = HWs[l];
      a.bx0[l] = cum;
      cum += (HWs[l] + 31) / 32;
    }
    a.bx0[4] = cum;
    dim3 grid(cum, 8, 2);
    dim3 block(8, 32);
    conv_nhwc_bf16<<<grid, block, 0, stream>>>(a);
    roi_gather_bf16<<<1024, 256, 0, stream>>>(a.dst[0], a.dst[1], a.dst[2], a.dst[3],
                                              p0, p1, out);
  } else {
    roi_gather_nchw<<<1024, 256, 0, stream>>>(f0, f1, f2, f3, p0, p1, out);
  }
}

// Round 3
// 200.480 us; speedup vs baseline: 1.1593x; 1.0443x over previous
//
#include <hip/hip_runtime.h>
#include <math.h>

#define C_CH 256
#define RESO 7
#define NBIN 49   // 7*7

// f32 -> bf16, round-to-nearest-even
__device__ __forceinline__ unsigned short f2bf(float f) {
  unsigned int u = __float_as_uint(f);
  u = (u + 0x7fffu + ((u >> 16) & 1u)) >> 16;
  return (unsigned short)u;
}
__device__ __forceinline__ float bf_lo(unsigned int u) { return __uint_as_float(u << 16); }
__device__ __forceinline__ float bf_hi(unsigned int u) { return __uint_as_float(u & 0xffff0000u); }

// ---------------------------------------------------------------------------
// Merged NCHW(f32) -> NHWC(bf16), all 4 levels, one dispatch.
// Tile: 64 channels x 64 hw.  Block = 256 threads.  Each thread: 4 float4
// loads (independent, in flight together), f32 LDS tile [64][65] (pitch 65
// => <=2-way banks both phases), bf16 pack + uint2 stores.
// ---------------------------------------------------------------------------
struct TArgs {
  const float* src[4];
  unsigned short* dst[4];
  int hw[4];
  int bx0[5];  // cumulative grid.x block start per level
};

__global__ __launch_bounds__(256) void conv_nhwc_bf16(TArgs a) {
  __shared__ float tile[64][65];
  const int bx = blockIdx.x;
  int l = 0;
  if (bx >= a.bx0[1]) l = 1;
  if (bx >= a.bx0[2]) l = 2;
  if (bx >= a.bx0[3]) l = 3;
  const int HW = a.hw[l];
  const int hw0 = (bx - a.bx0[l]) * 64;
  const int c0 = blockIdx.y * 64;
  const int n = blockIdx.z;

  const float* s = a.src[l] + (size_t)n * C_CH * HW;
  unsigned short* d = a.dst[l] + (size_t)n * HW * C_CH;

  const int t = threadIdx.x;
  const int lane16 = t & 15;   // column group
  const int row16 = t >> 4;    // row within 16-row stripe

  if (hw0 + 64 <= HW && (HW & 3) == 0) {
    // fast path: 4 independent float4 loads first, then LDS writes
    float4 v[4];
#pragma unroll
    for (int i = 0; i < 4; ++i) {
      const int c_l = row16 + 16 * i;
      v[i] = *(const float4*)(s + (size_t)(c0 + c_l) * HW + hw0 + lane16 * 4);
    }
#pragma unroll
    for (int i = 0; i < 4; ++i) {
      const int c_l = row16 + 16 * i;
      tile[c_l][lane16 * 4 + 0] = v[i].x;
      tile[c_l][lane16 * 4 + 1] = v[i].y;
      tile[c_l][lane16 * 4 + 2] = v[i].z;
      tile[c_l][lane16 * 4 + 3] = v[i].w;
    }
  } else {
    for (int i = 0; i < 4; ++i) {
      const int c_l = row16 + 16 * i;
      const float* row = s + (size_t)(c0 + c_l) * HW;
      for (int k = 0; k < 4; ++k) {
        const int hw = hw0 + lane16 * 4 + k;
        tile[c_l][lane16 * 4 + k] = (hw < HW) ? row[hw] : 0.0f;
      }
    }
  }
  __syncthreads();

  // store phase: thread -> (hw_l, 4-channel group); 128B contiguous / 16 lanes
#pragma unroll
  for (int i = 0; i < 4; ++i) {
    const int hw_l = row16 + 16 * i;
    const int hww = hw0 + hw_l;
    if (hww < HW) {
      const int c4 = lane16 * 4;
      const unsigned int lo = (unsigned int)f2bf(tile[c4 + 0][hw_l]) |
                              ((unsigned int)f2bf(tile[c4 + 1][hw_l]) << 16);
      const unsigned int hi = (unsigned int)f2bf(tile[c4 + 2][hw_l]) |
                              ((unsigned int)f2bf(tile[c4 + 3][hw_l]) << 16);
      *(uint2*)(d + (size_t)hww * C_CH + c0 + c4) = make_uint2(lo, hi);
    }
  }
}

// ---------------------------------------------------------------------------
// RoIAlign gather, bf16 NHWC.  512 threads (8 waves) per ROI; 50KB obuf ->
// 3 blocks/CU = 24 waves/CU.  Lane: cg=ln&31 (8 channels, uint4 taps),
// xt=ln>>5 (x-tap); shfl_xor(32) combines the two x-halves per bin.
// ---------------------------------------------------------------------------
__global__ __launch_bounds__(512) void roi_gather_bf16(
    const unsigned short* __restrict__ f0, const unsigned short* __restrict__ f1,
    const unsigned short* __restrict__ f2, const unsigned short* __restrict__ f3,
    const float* __restrict__ props0, const float* __restrict__ props1,
    float* __restrict__ out) {
  __shared__ float obuf[NBIN * C_CH];       // c-major: obuf[c*49 + bin]
  __shared__ int s_o0[2][14], s_o1[2][14];  // pre-scaled lo/hi offsets (0=y,1=x)
  __shared__ float s_w0[2][14], s_w1[2][14];

  const int r = blockIdx.x;
  const int t = threadIdx.x;
  const int b = (r >= 512) ? 1 : 0;
  const float* pr = (b ? props1 : props0) + (r & 511) * 4;
  const float x1 = pr[0], y1 = pr[1], x2 = pr[2], y2 = pr[3];

  // level assignment (match numpy f32 math exactly)
  const float size = sqrtf((x2 - x1 + 1.0f) * (y2 - y1 + 1.0f));
  float lv = floorf(4.0f + log2f(size / 224.0f + 1e-6f));
  lv = fminf(fmaxf(lv, 2.0f), 5.0f) - 2.0f;
  const int lvl = (int)lv;

  const int Htab[4] = {200, 100, 50, 25};
  const float stab[4] = {0.25f, 0.125f, 0.0625f, 0.03125f};
  const int H = Htab[lvl];
  const int W = H;
  const float sc = stab[lvl];
  const unsigned short* fl = (lvl == 0) ? f0 : (lvl == 1) ? f1 : (lvl == 2) ? f2 : f3;

  const float rx1 = x1 * sc, ry1 = y1 * sc;
  const float roi_w = fmaxf(x2 * sc - rx1, 1.0f);
  const float roi_h = fmaxf(y2 * sc - ry1, 1.0f);
  const float bw = roi_w / 7.0f, bh = roi_h / 7.0f;

  if (t < 28) {
    const int axis = t / 14;  // 0 = y, 1 = x
    const int k = t % 14;
    const float off = ((float)k + 0.5f) * 0.5f;
    const float v = axis ? (rx1 + off * bw) : (ry1 + off * bh);
    const int isz = H;
    const bool valid = (v >= -1.0f) && (v <= (float)isz);
    const float v0 = fmaxf(v, 0.0f);
    int lo = (int)floorf(v0);
    const bool edge = (lo >= isz - 1);
    lo = edge ? isz - 1 : lo;
    const int hi = edge ? isz - 1 : lo + 1;
    const float fr = edge ? 0.0f : (v0 - (float)lo);
    const int mul = axis ? C_CH : W * C_CH;
    s_o0[axis][k] = lo * mul;
    s_o1[axis][k] = hi * mul;
    s_w1[axis][k] = valid ? fr : 0.0f;
    s_w0[axis][k] = valid ? (1.0f - fr) : 0.0f;
  }
  __syncthreads();

  const int wv = t >> 6;   // wave 0..7: splits bins
  const int ln = t & 63;
  const int cg = ln & 31;  // channel group of 8
  const int xt = ln >> 5;  // which x-tap this half-wave takes
  const size_t HWp = (size_t)H * W;
  const unsigned short* base = fl + (size_t)b * HWp * C_CH + cg * 8;

  for (int bb = wv; bb < NBIN; bb += 8) {
    const int ph = bb / 7, pw = bb - ph * 7;
    float acc[8] = {0.f, 0.f, 0.f, 0.f, 0.f, 0.f, 0.f, 0.f};
#pragma unroll
    for (int s1 = 0; s1 < 2; ++s1) {
      const int sy = 2 * ph + s1;
      const int yo0 = s_o0[0][sy], yo1 = s_o1[0][sy];
      const float wy0 = s_w0[0][sy], wy1 = s_w1[0][sy];
#pragma unroll
      for (int s2 = 0; s2 < 2; ++s2) {
        const int sx = 2 * pw + s2;
        const int xo = xt ? s_o1[1][sx] : s_o0[1][sx];
        const float wx = xt ? s_w1[1][sx] : s_w0[1][sx];
        const uint4 q0 = *(const uint4*)(base + yo0 + xo);
        const uint4 q1 = *(const uint4*)(base + yo1 + xo);
        const float w0 = wx * wy0, w1 = wx * wy1;
        acc[0] += w0 * bf_lo(q0.x) + w1 * bf_lo(q1.x);
        acc[1] += w0 * bf_hi(q0.x) + w1 * bf_hi(q1.x);
        acc[2] += w0 * bf_lo(q0.y) + w1 * bf_lo(q1.y);
        acc[3] += w0 * bf_hi(q0.y) + w1 * bf_hi(q1.y);
        acc[4] += w0 * bf_lo(q0.z) + w1 * bf_lo(q1.z);
        acc[5] += w0 * bf_hi(q0.z) + w1 * bf_hi(q1.z);
        acc[6] += w0 * bf_lo(q0.w) + w1 * bf_lo(q1.w);
        acc[7] += w0 * bf_hi(q0.w) + w1 * bf_hi(q1.w);
      }
    }
    // combine the two x-tap halves
#pragma unroll
    for (int k = 0; k < 8; ++k) acc[k] += __shfl_xor(acc[k], 32);
    // each half writes its 4 channels
    const int cbase = cg * 8 + xt * 4;
#pragma unroll
    for (int k = 0; k < 4; ++k)
      obuf[(cbase + k) * NBIN + bb] = acc[xt * 4 + k] * 0.25f;
  }
  __syncthreads();

  // coalesced write-out: out[r] is 12544 contiguous floats
  float4* o4 = (float4*)(out + (size_t)r * (NBIN * C_CH));
  const float4* ob4 = (const float4*)obuf;
  for (int i = t; i < NBIN * C_CH / 4; i += 512) o4[i] = ob4[i];
}

// ---------------------------------------------------------------------------
// Fallback: direct NCHW f32 gather (used only if workspace is too small).
// ---------------------------------------------------------------------------
__global__ __launch_bounds__(256) void roi_gather_nchw(
    const float* __restrict__ f0, const float* __restrict__ f1,
    const float* __restrict__ f2, const float* __restrict__ f3,
    const float* __restrict__ props0, const float* __restrict__ props1,
    float* __restrict__ out) {
  __shared__ float obuf[NBIN * C_CH];
  __shared__ int s_o0[2][14], s_o1[2][14];
  __shared__ float s_w0[2][14], s_w1[2][14];

  const int r = blockIdx.x;
  const int t = threadIdx.x;
  const int b = (r >= 512) ? 1 : 0;
  const float* pr = (b ? props1 : props0) + (r & 511) * 4;
  const float x1 = pr[0], y1 = pr[1], x2 = pr[2], y2 = pr[3];
  const float size = sqrtf((x2 - x1 + 1.0f) * (y2 - y1 + 1.0f));
  float lv = floorf(4.0f + log2f(size / 224.0f + 1e-6f));
  lv = fminf(fmaxf(lv, 2.0f), 5.0f) - 2.0f;
  const int lvl = (int)lv;
  const int Htab[4] = {200, 100, 50, 25};
  const float stab[4] = {0.25f, 0.125f, 0.0625f, 0.03125f};
  const int H = Htab[lvl];
  const int W = H;
  const float sc = stab[lvl];
  const float* fl = (lvl == 0) ? f0 : (lvl == 1) ? f1 : (lvl == 2) ? f2 : f3;
  const float rx1 = x1 * sc, ry1 = y1 * sc;
  const float roi_w = fmaxf(x2 * sc - rx1, 1.0f);
  const float roi_h = fmaxf(y2 * sc - ry1, 1.0f);
  const float bw = roi_w / 7.0f, bh = roi_h / 7.0f;
  if (t < 28) {
    const int axis = t / 14;
    const int k = t % 14;
    const float off = ((float)k + 0.5f) * 0.5f;
    const float v = axis ? (rx1 + off * bw) : (ry1 + off * bh);
    const int isz = H;
    const bool valid = (v >= -1.0f) && (v <= (float)isz);
    const float v0 = fmaxf(v, 0.0f);
    int lo = (int)floorf(v0);
    const bool edge = (lo >= isz - 1);
    lo = edge ? isz - 1 : lo;
    const int hi = edge ? isz - 1 : lo + 1;
    const float fr = edge ? 0.0f : (v0 - (float)lo);
    const int mul = axis ? 1 : W;
    s_o0[axis][k] = lo * mul;
    s_o1[axis][k] = hi * mul;
    s_w1[axis][k] = valid ? fr : 0.0f;
    s_w0[axis][k] = valid ? (1.0f - fr) : 0.0f;
  }
  __syncthreads();
  const int wv = t >> 6;
  const int ln = t & 63;
  const size_t HWp = (size_t)H * W;
  const float* base = fl + ((size_t)b * C_CH + ln * 4) * HWp;
  for (int bb = wv; bb < NBIN; bb += 4) {
    const int ph = bb / 7, pw = bb - ph * 7;
    float4 acc = make_float4(0.f, 0.f, 0.f, 0.f);
    for (int s1 = 0; s1 < 2; ++s1) {
      const int sy = 2 * ph + s1;
      const int yo0 = s_o0[0][sy], yo1 = s_o1[0][sy];
      const float wy0 = s_w0[0][sy], wy1 = s_w1[0][sy];
      for (int s2 = 0; s2 < 2; ++s2) {
        const int sx = 2 * pw + s2;
        const int xo0 = s_o0[1][sx], xo1 = s_o1[1][sx];
        const float w00 = wy0 * s_w0[1][sx], w01 = wy0 * s_w1[1][sx];
        const float w10 = wy1 * s_w0[1][sx], w11 = wy1 * s_w1[1][sx];
        float e[4];
        for (int j = 0; j < 4; ++j) {
          e[j] = w00 * base[j * HWp + yo0 + xo0] + w01 * base[j * HWp + yo0 + xo1] +
                 w10 * base[j * HWp + yo1 + xo0] + w11 * base[j * HWp + yo1 + xo1];
        }
        acc.x += e[0]; acc.y += e[1]; acc.z += e[2]; acc.w += e[3];
      }
    }
    const int c4 = ln * 4;
    obuf[(c4 + 0) * NBIN + bb] = acc.x * 0.25f;
    obuf[(c4 + 1) * NBIN + bb] = acc.y * 0.25f;
    obuf[(c4 + 2) * NBIN + bb] = acc.z * 0.25f;
    obuf[(c4 + 3) * NBIN + bb] = acc.w * 0.25f;
  }
  __syncthreads();
  float4* o4 = (float4*)(out + (size_t)r * (NBIN * C_CH));
  const float4* ob4 = (const float4*)obuf;
  for (int i = t; i < NBIN * C_CH / 4; i += 256) o4[i] = ob4[i];
}

// ---------------------------------------------------------------------------
extern "C" void kernel_launch(void* const* d_in, const int* in_sizes, int n_in,
                              void* d_out, int out_size, void* d_ws, size_t ws_size,
                              hipStream_t stream) {
  const float* f0 = (const float*)d_in[0];
  const float* f1 = (const float*)d_in[1];
  const float* f2 = (const float*)d_in[2];
  const float* f3 = (const float*)d_in[3];
  // d_in[4] (feat4, 13x13) unused by reference
  const float* p0 = (const float*)d_in[5];
  const float* p1 = (const float*)d_in[6];
  float* out = (float*)d_out;
  unsigned short* ws = (unsigned short*)d_ws;

  const int HWs[4] = {200 * 200, 100 * 100, 50 * 50, 25 * 25};
  size_t off[4];
  size_t acc = 0;
  for (int l = 0; l < 4; ++l) {
    off[l] = acc;
    acc += (size_t)2 * C_CH * HWs[l];
  }
  const size_t need_bytes = acc * sizeof(unsigned short);  // ~54.4 MB

  if (ws_size >= need_bytes) {
    TArgs a;
    a.src[0] = f0; a.src[1] = f1; a.src[2] = f2; a.src[3] = f3;
    int cum = 0;
    for (int l = 0; l < 4; ++l) {
      a.dst[l] = ws + off[l];
      a.hw[l] = HWs[l];
      a.bx0[l] = cum;
      cum += (HWs[l] + 63) / 64;
    }
    a.bx0[4] = cum;
    dim3 grid(cum, 4, 2);
    dim3 block(256);
    conv_nhwc_bf16<<<grid, block, 0, stream>>>(a);
    roi_gather_bf16<<<1024, 512, 0, stream>>>(a.dst[0], a.dst[1], a.dst[2], a.dst[3],
                                              p0, p1, out);
  } else {
    roi_gather_nchw<<<1024, 256, 0, stream>>>(f0, f1, f2, f3, p0, p1, out);
  }
}

// Round 5
// 188.525 us; speedup vs baseline: 1.2328x; 1.0634x over previous
//
#include <hip/hip_runtime.h>
#include <math.h>

#define C_CH 256
#define RESO 7
#define NBIN 49   // 7*7

typedef float fx4 __attribute__((ext_vector_type(4)));
typedef unsigned int ux2 __attribute__((ext_vector_type(2)));

// f32 -> bf16, round-to-nearest-even
__device__ __forceinline__ unsigned short f2bf(float f) {
  unsigned int u = __float_as_uint(f);
  u = (u + 0x7fffu + ((u >> 16) & 1u)) >> 16;
  return (unsigned short)u;
}
__device__ __forceinline__ float bf_lo(unsigned int u) { return __uint_as_float(u << 16); }
__device__ __forceinline__ float bf_hi(unsigned int u) { return __uint_as_float(u & 0xffff0000u); }

// ---------------------------------------------------------------------------
// Merged NCHW(f32) -> NHWC(bf16), all 4 levels, ONE persistent dispatch.
// 2048 blocks x 256 thr, grid-stride over 64c x 64hw tiles, software
// pipeline: tile k+1's 4 float4 loads are issued before the barrier that
// precedes tile k's LDS-read/pack/store phase, so global loads stay in
// flight through the whole store phase (register double-buffer).
// ---------------------------------------------------------------------------
struct TArgs {
  const float* src[4];
  unsigned short* dst[4];
  int hw[4];
  int tilesx[4];  // ceil(hw/64)
  int tbase[5];   // cumulative tiles per level (tilesx*4*2)
  int total;
};

__device__ __forceinline__ void decode_tile(const TArgs& a, int T, int& l, int& hw0,
                                            int& c0, int& n, int& HW) {
  int ll = 0;
  if (T >= a.tbase[1]) ll = 1;
  if (T >= a.tbase[2]) ll = 2;
  if (T >= a.tbase[3]) ll = 3;
  const int idx = T - a.tbase[ll];
  const int txs = a.tilesx[ll];
  const int tx = idx % txs;
  const int rem = idx / txs;
  l = ll;
  hw0 = tx * 64;
  c0 = (rem & 3) * 64;
  n = rem >> 2;
  HW = a.hw[ll];
}

__device__ __forceinline__ void load_tile(const TArgs& a, int l, int hw0, int c0, int n,
                                          int HW, int lane16, int row16, fx4 v[4]) {
  const float* s = a.src[l] + (size_t)n * C_CH * HW;
  if (((HW & 3) == 0) && (hw0 + 64 <= HW)) {
#pragma unroll
    for (int i = 0; i < 4; ++i) {
      const int c_l = row16 + 16 * i;
      v[i] = __builtin_nontemporal_load(
          (const fx4*)(s + (size_t)(c0 + c_l) * HW + hw0 + lane16 * 4));
    }
  } else {
#pragma unroll
    for (int i = 0; i < 4; ++i) {
      const int c_l = row16 + 16 * i;
      const float* row = s + (size_t)(c0 + c_l) * HW;
#pragma unroll
      for (int k = 0; k < 4; ++k) {
        const int hw = hw0 + lane16 * 4 + k;
        v[i][k] = (hw < HW) ? row[hw] : 0.0f;
      }
    }
  }
}

__global__ __launch_bounds__(256) void conv_nhwc_bf16(TArgs a) {
  __shared__ float tile[64][65];
  const int t = threadIdx.x;
  const int lane16 = t & 15;
  const int row16 = t >> 4;
  const int stride = gridDim.x;

  int T = blockIdx.x;
  int l0, hw00, c00, n0, HW0;
  decode_tile(a, T, l0, hw00, c00, n0, HW0);
  fx4 v[4];
  load_tile(a, l0, hw00, c00, n0, HW0, lane16, row16, v);

  while (true) {
    __syncthreads();  // previous store phase done reading LDS
#pragma unroll
    for (int i = 0; i < 4; ++i) {
      const int c_l = row16 + 16 * i;
      tile[c_l][lane16 * 4 + 0] = v[i][0];
      tile[c_l][lane16 * 4 + 1] = v[i][1];
      tile[c_l][lane16 * 4 + 2] = v[i][2];
      tile[c_l][lane16 * 4 + 3] = v[i][3];
    }

    // prefetch next tile BEFORE the barrier -> loads overlap store phase
    const int Tn = T + stride;
    const bool more = Tn < a.total;
    int l1, hw01, c01, n1, HW1;
    fx4 w[4];
    if (more) {
      decode_tile(a, Tn, l1, hw01, c01, n1, HW1);
      load_tile(a, l1, hw01, c01, n1, HW1, lane16, row16, w);
    }
    __syncthreads();

    // store phase for tile T
    unsigned short* d = a.dst[l0] + (size_t)n0 * HW0 * C_CH;
#pragma unroll
    for (int i = 0; i < 4; ++i) {
      const int hw_l = row16 + 16 * i;
      const int hww = hw00 + hw_l;
      if (hww < HW0) {
        const int c4 = lane16 * 4;
        ux2 p;
        p.x = (unsigned int)f2bf(tile[c4 + 0][hw_l]) |
              ((unsigned int)f2bf(tile[c4 + 1][hw_l]) << 16);
        p.y = (unsigned int)f2bf(tile[c4 + 2][hw_l]) |
              ((unsigned int)f2bf(tile[c4 + 3][hw_l]) << 16);
        *(ux2*)(d + (size_t)hww * C_CH + c00 + c4) = p;
      }
    }

    if (!more) break;
    T = Tn;
    l0 = l1; hw00 = hw01; c00 = c01; n0 = n1; HW0 = HW1;
#pragma unroll
    for (int i = 0; i < 4; ++i) v[i] = w[i];
  }
}

// ---------------------------------------------------------------------------
// RoIAlign gather, bf16 NHWC.  512 threads (8 waves) per ROI; 50KB obuf ->
// 3 blocks/CU = 24 waves/CU.  Lane: cg=ln&31 (8 channels, uint4 taps),
// xt=ln>>5 (x-tap); shfl_xor(32) combines the two x-halves per bin.
// ---------------------------------------------------------------------------
__global__ __launch_bounds__(512) void roi_gather_bf16(
    const unsigned short* __restrict__ f0, const unsigned short* __restrict__ f1,
    const unsigned short* __restrict__ f2, const unsigned short* __restrict__ f3,
    const float* __restrict__ props0, const float* __restrict__ props1,
    float* __restrict__ out) {
  __shared__ float obuf[NBIN * C_CH];       // c-major: obuf[c*49 + bin]
  __shared__ int s_o0[2][14], s_o1[2][14];  // pre-scaled lo/hi offsets (0=y,1=x)
  __shared__ float s_w0[2][14], s_w1[2][14];

  const int r = blockIdx.x;
  const int t = threadIdx.x;
  const int b = (r >= 512) ? 1 : 0;
  const float* pr = (b ? props1 : props0) + (r & 511) * 4;
  const float x1 = pr[0], y1 = pr[1], x2 = pr[2], y2 = pr[3];

  // level assignment (match numpy f32 math exactly)
  const float size = sqrtf((x2 - x1 + 1.0f) * (y2 - y1 + 1.0f));
  float lv = floorf(4.0f + log2f(size / 224.0f + 1e-6f));
  lv = fminf(fmaxf(lv, 2.0f), 5.0f) - 2.0f;
  const int lvl = (int)lv;

  const int Htab[4] = {200, 100, 50, 25};
  const float stab[4] = {0.25f, 0.125f, 0.0625f, 0.03125f};
  const int H = Htab[lvl];
  const int W = H;
  const float sc = stab[lvl];
  const unsigned short* fl = (lvl == 0) ? f0 : (lvl == 1) ? f1 : (lvl == 2) ? f2 : f3;

  const float rx1 = x1 * sc, ry1 = y1 * sc;
  const float roi_w = fmaxf(x2 * sc - rx1, 1.0f);
  const float roi_h = fmaxf(y2 * sc - ry1, 1.0f);
  const float bw = roi_w / 7.0f, bh = roi_h / 7.0f;

  if (t < 28) {
    const int axis = t / 14;  // 0 = y, 1 = x
    const int k = t % 14;
    const float off = ((float)k + 0.5f) * 0.5f;
    const float v = axis ? (rx1 + off * bw) : (ry1 + off * bh);
    const int isz = H;
    const bool valid = (v >= -1.0f) && (v <= (float)isz);
    const float v0 = fmaxf(v, 0.0f);
    int lo = (int)floorf(v0);
    const bool edge = (lo >= isz - 1);
    lo = edge ? isz - 1 : lo;
    const int hi = edge ? isz - 1 : lo + 1;
    const float fr = edge ? 0.0f : (v0 - (float)lo);
    const int mul = axis ? C_CH : W * C_CH;
    s_o0[axis][k] = lo * mul;
    s_o1[axis][k] = hi * mul;
    s_w1[axis][k] = valid ? fr : 0.0f;
    s_w0[axis][k] = valid ? (1.0f - fr) : 0.0f;
  }
  __syncthreads();

  const int wv = t >> 6;   // wave 0..7: splits bins
  const int ln = t & 63;
  const int cg = ln & 31;  // channel group of 8
  const int xt = ln >> 5;  // which x-tap this half-wave takes
  const size_t HWp = (size_t)H * W;
  const unsigned short* base = fl + (size_t)b * HWp * C_CH + cg * 8;

  for (int bb = wv; bb < NBIN; bb += 8) {
    const int ph = bb / 7, pw = bb - ph * 7;
    float acc[8] = {0.f, 0.f, 0.f, 0.f, 0.f, 0.f, 0.f, 0.f};
#pragma unroll
    for (int s1 = 0; s1 < 2; ++s1) {
      const int sy = 2 * ph + s1;
      const int yo0 = s_o0[0][sy], yo1 = s_o1[0][sy];
      const float wy0 = s_w0[0][sy], wy1 = s_w1[0][sy];
#pragma unroll
      for (int s2 = 0; s2 < 2; ++s2) {
        const int sx = 2 * pw + s2;
        const int xo = xt ? s_o1[1][sx] : s_o0[1][sx];
        const float wx = xt ? s_w1[1][sx] : s_w0[1][sx];
        const uint4 q0 = *(const uint4*)(base + yo0 + xo);
        const uint4 q1 = *(const uint4*)(base + yo1 + xo);
        const float w0 = wx * wy0, w1 = wx * wy1;
        acc[0] += w0 * bf_lo(q0.x) + w1 * bf_lo(q1.x);
        acc[1] += w0 * bf_hi(q0.x) + w1 * bf_hi(q1.x);
        acc[2] += w0 * bf_lo(q0.y) + w1 * bf_lo(q1.y);
        acc[3] += w0 * bf_hi(q0.y) + w1 * bf_hi(q1.y);
        acc[4] += w0 * bf_lo(q0.z) + w1 * bf_lo(q1.z);
        acc[5] += w0 * bf_hi(q0.z) + w1 * bf_hi(q1.z);
        acc[6] += w0 * bf_lo(q0.w) + w1 * bf_lo(q1.w);
        acc[7] += w0 * bf_hi(q0.w) + w1 * bf_hi(q1.w);
      }
    }
    // combine the two x-tap halves
#pragma unroll
    for (int k = 0; k < 8; ++k) acc[k] += __shfl_xor(acc[k], 32);
    // each half writes its 4 channels
    const int cbase = cg * 8 + xt * 4;
#pragma unroll
    for (int k = 0; k < 4; ++k)
      obuf[(cbase + k) * NBIN + bb] = acc[xt * 4 + k] * 0.25f;
  }
  __syncthreads();

  // coalesced write-out: out[r] is 12544 contiguous floats
  fx4* o4 = (fx4*)(out + (size_t)r * (NBIN * C_CH));
  const fx4* ob4 = (const fx4*)obuf;
  for (int i = t; i < NBIN * C_CH / 4; i += 512)
    __builtin_nontemporal_store(ob4[i], o4 + i);
}

// ---------------------------------------------------------------------------
// Fallback: direct NCHW f32 gather (used only if workspace is too small).
// ---------------------------------------------------------------------------
__global__ __launch_bounds__(256) void roi_gather_nchw(
    const float* __restrict__ f0, const float* __restrict__ f1,
    const float* __restrict__ f2, const float* __restrict__ f3,
    const float* __restrict__ props0, const float* __restrict__ props1,
    float* __restrict__ out) {
  __shared__ float obuf[NBIN * C_CH];
  __shared__ int s_o0[2][14], s_o1[2][14];
  __shared__ float s_w0[2][14], s_w1[2][14];

  const int r = blockIdx.x;
  const int t = threadIdx.x;
  const int b = (r >= 512) ? 1 : 0;
  const float* pr = (b ? props1 : props0) + (r & 511) * 4;
  const float x1 = pr[0], y1 = pr[1], x2 = pr[2], y2 = pr[3];
  const float size = sqrtf((x2 - x1 + 1.0f) * (y2 - y1 + 1.0f));
  float lv = floorf(4.0f + log2f(size / 224.0f + 1e-6f));
  lv = fminf(fmaxf(lv, 2.0f), 5.0f) - 2.0f;
  const int lvl = (int)lv;
  const int Htab[4] = {200, 100, 50, 25};
  const float stab[4] = {0.25f, 0.125f, 0.0625f, 0.03125f};
  const int H = Htab[lvl];
  const int W = H;
  const float sc = stab[lvl];
  const float* fl = (lvl == 0) ? f0 : (lvl == 1) ? f1 : (lvl == 2) ? f2 : f3;
  const float rx1 = x1 * sc, ry1 = y1 * sc;
  const float roi_w = fmaxf(x2 * sc - rx1, 1.0f);
  const float roi_h = fmaxf(y2 * sc - ry1, 1.0f);
  const float bw = roi_w / 7.0f, bh = roi_h / 7.0f;
  if (t < 28) {
    const int axis = t / 14;
    const int k = t % 14;
    const float off = ((float)k + 0.5f) * 0.5f;
    const float v = axis ? (rx1 + off * bw) : (ry1 + off * bh);
    const int isz = H;
    const bool valid = (v >= -1.0f) && (v <= (float)isz);
    const float v0 = fmaxf(v, 0.0f);
    int lo = (int)floorf(v0);
    const bool edge = (lo >= isz - 1);
    lo = edge ? isz - 1 : lo;
    const int hi = edge ? isz - 1 : lo + 1;
    const float fr = edge ? 0.0f : (v0 - (float)lo);
    const int mul = axis ? 1 : W;
    s_o0[axis][k] = lo * mul;
    s_o1[axis][k] = hi * mul;
    s_w1[axis][k] = valid ? fr : 0.0f;
    s_w0[axis][k] = valid ? (1.0f - fr) : 0.0f;
  }
  __syncthreads();
  const int wv = t >> 6;
  const int ln = t & 63;
  const size_t HWp = (size_t)H * W;
  const float* base = fl + ((size_t)b * C_CH + ln * 4) * HWp;
  for (int bb = wv; bb < NBIN; bb += 4) {
    const int ph = bb / 7, pw = bb - ph * 7;
    float4 acc = make_float4(0.f, 0.f, 0.f, 0.f);
    for (int s1 = 0; s1 < 2; ++s1) {
      const int sy = 2 * ph + s1;
      const int yo0 = s_o0[0][sy], yo1 = s_o1[0][sy];
      const float wy0 = s_w0[0][sy], wy1 = s_w1[0][sy];
      for (int s2 = 0; s2 < 2; ++s2) {
        const int sx = 2 * pw + s2;
        const int xo0 = s_o0[1][sx], xo1 = s_o1[1][sx];
        const float w00 = wy0 * s_w0[1][sx], w01 = wy0 * s_w1[1][sx];
        const float w10 = wy1 * s_w0[1][sx], w11 = wy1 * s_w1[1][sx];
        float e[4];
        for (int j = 0; j < 4; ++j) {
          e[j] = w00 * base[j * HWp + yo0 + xo0] + w01 * base[j * HWp + yo0 + xo1] +
                 w10 * base[j * HWp + yo1 + xo0] + w11 * base[j * HWp + yo1 + xo1];
        }
        acc.x += e[0]; acc.y += e[1]; acc.z += e[2]; acc.w += e[3];
      }
    }
    const int c4 = ln * 4;
    obuf[(c4 + 0) * NBIN + bb] = acc.x * 0.25f;
    obuf[(c4 + 1) * NBIN + bb] = acc.y * 0.25f;
    obuf[(c4 + 2) * NBIN + bb] = acc.z * 0.25f;
    obuf[(c4 + 3) * NBIN + bb] = acc.w * 0.25f;
  }
  __syncthreads();
  float4* o4 = (float4*)(out + (size_t)r * (NBIN * C_CH));
  const float4* ob4 = (const float4*)obuf;
  for (int i = t; i < NBIN * C_CH / 4; i += 256) o4[i] = ob4[i];
}

// ---------------------------------------------------------------------------
extern "C" void kernel_launch(void* const* d_in, const int* in_sizes, int n_in,
                              void* d_out, int out_size, void* d_ws, size_t ws_size,
                              hipStream_t stream) {
  const float* f0 = (const float*)d_in[0];
  const float* f1 = (const float*)d_in[1];
  const float* f2 = (const float*)d_in[2];
  const float* f3 = (const float*)d_in[3];
  // d_in[4] (feat4, 13x13) unused by reference
  const float* p0 = (const float*)d_in[5];
  const float* p1 = (const float*)d_in[6];
  float* out = (float*)d_out;
  unsigned short* ws = (unsigned short*)d_ws;

  const int HWs[4] = {200 * 200, 100 * 100, 50 * 50, 25 * 25};
  size_t off[4];
  size_t acc = 0;
  for (int l = 0; l < 4; ++l) {
    off[l] = acc;
    acc += (size_t)2 * C_CH * HWs[l];
  }
  const size_t need_bytes = acc * sizeof(unsigned short);  // ~54.4 MB

  if (ws_size >= need_bytes) {
    TArgs a;
    a.src[0] = f0; a.src[1] = f1; a.src[2] = f2; a.src[3] = f3;
    int cum = 0;
    for (int l = 0; l < 4; ++l) {
      a.dst[l] = ws + off[l];
      a.hw[l] = HWs[l];
      a.tilesx[l] = (HWs[l] + 63) / 64;
      a.tbase[l] = cum;
      cum += a.tilesx[l] * 4 * 2;
    }
    a.tbase[4] = cum;
    a.total = cum;  // 6656
    const int nblocks = (cum < 2048) ? cum : 2048;
    conv_nhwc_bf16<<<nblocks, 256, 0, stream>>>(a);
    roi_gather_bf16<<<1024, 512, 0, stream>>>(a.dst[0], a.dst[1], a.dst[2], a.dst[3],
                                              p0, p1, out);
  } else {
    roi_gather_nchw<<<1024, 256, 0, stream>>>(f0, f1, f2, f3, p0, p1, out);
  }
}